// Round 6
// baseline (1822.194 us; speedup 1.0000x reference)
//
#include <hip/hip_runtime.h>
#include <math.h>

#define HH 64
#define WW 96
#define NPX (HH*WW)        // 6144
#define CIN 1024
#define CMID 512
#define NA 9
#define NANCH (NPX*NA)     // 55296
#define PRE_NMS 6000
#define POST_NMS 300
#define NEGV -1e9f
#define NBINS 16384
#define BUFCAP 8192
#define MASKW 94           // ceil(6000/64)

// conv3 tiling
#define OCT 8
#define CCH 4
#define CSPL 4
#define CPB (CIN/CSPL)     // 256
#define LSTR 38            // LDS row stride
#define NS 19              // staging slots per thread (4*34*34 = 4624 <= 19*256)
#define WSLOTS (OCT*CCH*9) // 288 weight slots

// conv1x1 tiling
#define K2_CS 16
#define K2_CC (CMID/K2_CS) // 32

__constant__ float c_anch[9][4] = {
    {-84.f, -40.f,  99.f,  55.f},
    {-176.f,-88.f, 191.f, 103.f},
    {-360.f,-184.f,375.f, 199.f},
    {-56.f, -56.f,  71.f,  71.f},
    {-120.f,-120.f,135.f, 135.f},
    {-248.f,-248.f,263.f, 263.f},
    {-36.f, -80.f,  51.f,  95.f},
    {-80.f,-168.f,  95.f, 183.f},
    {-168.f,-344.f,183.f, 359.f}
};

__device__ __forceinline__ unsigned int fkey(float f) {
    unsigned int b = __float_as_uint(f);
    return (b & 0x80000000u) ? ~b : (b | 0x80000000u);
}
__device__ __forceinline__ float fkey_inv(unsigned int k) {
    unsigned int b = (k & 0x80000000u) ? (k & 0x7fffffffu) : ~k;
    return __uint_as_float(b);
}
__device__ __forceinline__ int score_bin(float s) {
    if (!(s > 0.f)) return 0;
    int b = (int)(s * (float)NBINS);
    return b > NBINS - 1 ? NBINS - 1 : b;
}

// ---------------- K1: 3x3 conv partials ----------------
// Round-5 structure with the weight-staging bug fixed: 288 slots are staged
// by 256 threads via two hoisted slots per thread (tid and tid+256 when <288).
// Round-5 bug: `if (tid < 288)` staged only 256 slots -> wS[7][*][4..] garbage.
__global__ __launch_bounds__(256, 4) void conv3_part(const float* __restrict__ x,
                                                     const float* __restrict__ w,
                                                     float* __restrict__ part) {
    __shared__ float inS[CCH][34][LSTR];   // 20672 B
    __shared__ float wS[OCT][CCH][12];     // 1536 B, 16B-aligned rows
    int tid = threadIdx.x;
    int ocb = blockIdx.x * OCT;
    int sp = blockIdx.y;                // 0..5
    int ty0 = (sp / 3) * 32, tx0 = (sp % 3) * 32;
    int cs = blockIdx.z;
    int c0 = cs * CPB;
    int lx = (tid & 15) * 2, ly = (tid >> 4) * 2;

    // hoisted staging pattern: pk = (global_offset<<16) | lds_offset
    // global_offset < 4*6144 = 24576 (15b); lds_offset < 4*34*38 = 5168 (13b)
    int pk[NS];
#pragma unroll
    for (int s = 0; s < NS; s++) {
        int idx = tid + s * 256;
        int c = idx / 1156;
        int rr = idx - c * 1156;
        int r = rr / 34;
        int col = rr - r * 34;
        int gy = ty0 + r - 1, gx = tx0 + col - 1;
        bool ok = (idx < 4624) && (gy >= 0) && (gy < HH) && (gx >= 0) && (gx < WW);
        int go = ok ? (c * NPX + gy * WW + gx) : 0;
        int la = ok ? ((c * 34 + r) * LSTR + col) : (LSTR - 1);  // col 37: never read
        pk[s] = (go << 16) | la;
    }
    // hoisted weight-staging pattern: slots tid and tid+256 (288 total)
    int wgoff0, wlds0, wgoff1, wlds1;
    {
        int i = tid;
        int o = i / 36, rem = i - o * 36, c = rem / 9, k = rem - c * 9;
        wgoff0 = (o * CIN + c) * 9 + k;
        wlds0 = (o * CCH + c) * 12 + k;
        int i2 = tid + 256;
        int o2 = i2 / 36, rem2 = i2 - o2 * 36, c2 = rem2 / 9, k2 = rem2 - c2 * 9;
        wgoff1 = (o2 * CIN + c2) * 9 + k2;
        wlds1 = (o2 * CCH + c2) * 12 + k2;
    }

    // pre-zero input tile (border + pad stay 0 forever)
    for (int i = tid; i < CCH * 34 * LSTR; i += 256) ((float*)inS)[i] = 0.f;

    float acc[OCT][4];
#pragma unroll
    for (int o = 0; o < OCT; o++)
#pragma unroll
        for (int p = 0; p < 4; p++) acc[o][p] = 0.f;

    const float* wbase0 = w + ((size_t)ocb * CIN + c0) * 9;

    for (int cc = 0; cc < CPB; cc += CCH) {
        // issue global loads (input slab + weight block)
        const float* xb = x + (size_t)(c0 + cc) * NPX;
        float sv[NS];
#pragma unroll
        for (int s = 0; s < NS; s++) sv[s] = xb[pk[s] >> 16];
        float wv0 = wbase0[(size_t)cc * 9 + wgoff0];
        float wv1 = (tid < WSLOTS - 256) ? wbase0[(size_t)cc * 9 + wgoff1] : 0.f;

        __syncthreads();   // previous iteration's LDS reads complete
#pragma unroll
        for (int s = 0; s < NS; s++) ((float*)inS)[pk[s] & 0xffff] = sv[s];
        ((float*)wS)[wlds0] = wv0;
        if (tid < WSLOTS - 256) ((float*)wS)[wlds1] = wv1;
        __syncthreads();   // staged data visible

        for (int c = 0; c < CCH; c++) {
            float iv[4][4];
            const float* lrow = &inS[c][ly][lx];
#pragma unroll
            for (int r = 0; r < 4; r++) {
                float2 a = *(const float2*)&lrow[r * LSTR];
                float2 b = *(const float2*)&lrow[r * LSTR + 2];
                iv[r][0] = a.x; iv[r][1] = a.y; iv[r][2] = b.x; iv[r][3] = b.y;
            }
#pragma unroll
            for (int o = 0; o < OCT; o++) {
                float4 w03 = *(const float4*)&wS[o][c][0];
                float4 w47 = *(const float4*)&wS[o][c][4];
                float w8 = wS[o][c][8];
                float wk[9] = {w03.x, w03.y, w03.z, w03.w,
                               w47.x, w47.y, w47.z, w47.w, w8};
#pragma unroll
                for (int ky = 0; ky < 3; ky++)
#pragma unroll
                    for (int kx = 0; kx < 3; kx++) {
                        float wv2 = wk[ky * 3 + kx];
                        acc[o][0] += iv[0 + ky][0 + kx] * wv2;
                        acc[o][1] += iv[0 + ky][1 + kx] * wv2;
                        acc[o][2] += iv[1 + ky][0 + kx] * wv2;
                        acc[o][3] += iv[1 + ky][1 + kx] * wv2;
                    }
            }
        }
    }
#pragma unroll
    for (int o = 0; o < OCT; o++)
#pragma unroll
        for (int p = 0; p < 4; p++) {
            int gy = ty0 + ly + (p >> 1), gx = tx0 + lx + (p & 1);
            part[((size_t)cs * CMID + ocb + o) * NPX + gy * WW + gx] = acc[o][p];
        }
}

// ---------------- K1b: reduce + bias + relu ----------------
__global__ __launch_bounds__(256) void bias_relu(const float* __restrict__ part,
                                                 const float* __restrict__ b1,
                                                 float* __restrict__ h) {
    int i = blockIdx.x * 256 + threadIdx.x;
    if (i >= CMID * NPX) return;
    int oc = i / NPX;
    float s = part[i] + part[(size_t)CMID * NPX + i] +
              part[2 * (size_t)CMID * NPX + i] + part[3 * (size_t)CMID * NPX + i] + b1[oc];
    h[i] = s > 0.f ? s : 0.f;
}

// ---------------- K2: 1x1 convs (c-split partials) ----------------
__global__ __launch_bounds__(256) void conv1x1_part(const float* __restrict__ h,
                                                    const float* __restrict__ wc,
                                                    const float* __restrict__ wb,
                                                    float* __restrict__ psum) {
    __shared__ float wT[K2_CC][56];
    int tid = threadIdx.x;
    int px = blockIdx.x * 256 + tid;
    int g = blockIdx.y;
    int cb = g * K2_CC;
    for (int i = tid; i < K2_CC * 54; i += 256) {
        int c = i / 54, o = i - c * 54;
        float wv = (o < 18) ? wc[o * CMID + cb + c] : wb[(o - 18) * CMID + cb + c];
        wT[c][o] = wv;
    }
    __syncthreads();
    float acc[54];
#pragma unroll
    for (int o = 0; o < 54; o++) acc[o] = 0.f;
    for (int c = 0; c < K2_CC; c++) {
        float hv = h[(size_t)(cb + c) * NPX + px];
#pragma unroll
        for (int o = 0; o < 54; o++) acc[o] += wT[c][o] * hv;
    }
    for (int o = 0; o < 54; o++)
        psum[((size_t)g * 54 + o) * NPX + px] = acc[o];
}

__global__ __launch_bounds__(256) void conv1x1_reduce(const float* __restrict__ psum,
                                                      const float* __restrict__ bc,
                                                      const float* __restrict__ bb,
                                                      float* __restrict__ sd) {
    int i = blockIdx.x * 256 + threadIdx.x;
    if (i >= 54 * NPX) return;
    int o = i / NPX;
    float s = (o < 18) ? bc[o] : bb[o - 18];
    for (int g = 0; g < K2_CS; g++) s += psum[(size_t)g * 54 * NPX + i];
    sd[i] = s;
}

// ---------------- K3: proposals + histogram ----------------
__global__ __launch_bounds__(256) void proposals_k(const float* __restrict__ sd,
                                                   const float* __restrict__ info,
                                                   float* __restrict__ props,
                                                   float* __restrict__ scv,
                                                   unsigned int* __restrict__ hist) {
    int i = blockIdx.x * 256 + threadIdx.x;
    if (i >= NANCH) return;
    int a = i % NA;
    int p = i / NA;
    int hy = p / WW, wx = p - hy * WW;

    float s0 = sd[a * NPX + p], s1 = sd[(a + NA) * NPX + p];
    float m = fmaxf(s0, s1);
    float e0 = expf(s0 - m), e1 = expf(s1 - m);
    float fg = e1 / (e0 + e1);

    float d0 = sd[(18 + 4 * a + 0) * NPX + p];
    float d1 = sd[(18 + 4 * a + 1) * NPX + p];
    float d2 = sd[(18 + 4 * a + 2) * NPX + p];
    float d3 = sd[(18 + 4 * a + 3) * NPX + p];

    float sx = wx * 16.f, sy = hy * 16.f;
    float ax1 = c_anch[a][0] + sx, ay1 = c_anch[a][1] + sy;
    float ax2 = c_anch[a][2] + sx, ay2 = c_anch[a][3] + sy;
    float wdt = ax2 - ax1 + 1.f;
    float hgt = ay2 - ay1 + 1.f;
    float cx = ax1 + 0.5f * wdt;
    float cy = ay1 + 0.5f * hgt;
    float pcx = d0 * wdt + cx;
    float pcy = d1 * hgt + cy;
    float pw = expf(d2) * wdt;
    float ph = expf(d3) * hgt;

    float imh = info[0], imw = info[1], iscale = info[2];
    float x1 = fminf(fmaxf(pcx - 0.5f * pw, 0.f), imw - 1.f);
    float y1 = fminf(fmaxf(pcy - 0.5f * ph, 0.f), imh - 1.f);
    float x2 = fminf(fmaxf(pcx + 0.5f * pw, 0.f), imw - 1.f);
    float y2 = fminf(fmaxf(pcy + 0.5f * ph, 0.f), imh - 1.f);

    float ms = 16.f * iscale;
    bool valid = ((x2 - x1 + 1.f) >= ms) && ((y2 - y1 + 1.f) >= ms);
    float s = valid ? fg : NEGV;

    props[(size_t)i * 4 + 0] = x1;
    props[(size_t)i * 4 + 1] = y1;
    props[(size_t)i * 4 + 2] = x2;
    props[(size_t)i * 4 + 3] = y2;
    scv[i] = s;
    atomicAdd(&hist[score_bin(s)], 1u);
}

// ---------------- K4: find threshold bin ----------------
__global__ __launch_bounds__(1024) void scan_hist(const unsigned int* __restrict__ hist,
                                                  unsigned int* __restrict__ params) {
    __shared__ unsigned int psum[1024];
    int tid = threadIdx.x;
    unsigned int s = 0;
    for (int k = 0; k < 16; k++) s += hist[tid * 16 + k];
    psum[tid] = s;
    __syncthreads();
    if (tid == 0) {
        unsigned int run = 0;
        int B = 0;
        int t;
        for (t = 1023; t >= 0; t--) {
            if (run + psum[t] >= PRE_NMS) break;
            run += psum[t];
        }
        if (t >= 0) {
            unsigned int r2 = run;
            B = t * 16;
            for (int b = t * 16 + 15; b >= t * 16; b--) {
                r2 += hist[b];
                if (r2 >= PRE_NMS) { B = b; break; }
            }
        }
        params[0] = (unsigned int)B;
    }
}

// ---------------- K5: gather candidates ----------------
__global__ __launch_bounds__(256) void gather_top(const float* __restrict__ scv,
                                                  const unsigned int* __restrict__ params,
                                                  unsigned long long* __restrict__ buf,
                                                  unsigned int* __restrict__ counter) {
    int i = blockIdx.x * 256 + threadIdx.x;
    if (i >= NANCH) return;
    float s = scv[i];
    if (score_bin(s) >= (int)params[0]) {
        unsigned int pos = atomicAdd(counter, 1u);
        if (pos < BUFCAP) {
            unsigned long long key = ((unsigned long long)fkey(s) << 32) |
                                     (unsigned int)(~(unsigned int)i);
            buf[pos] = key;
        }
    }
}

// ---------------- K6: bitonic sort, emit top-6000 ----------------
__global__ __launch_bounds__(1024) void sort_top(unsigned long long* __restrict__ buf,
                                                 const unsigned int* __restrict__ counter,
                                                 const float* __restrict__ props,
                                                 float* __restrict__ top_boxes,
                                                 float* __restrict__ top_sc) {
    __shared__ unsigned long long arr[BUFCAP];   // 64 KiB
    int tid = threadIdx.x;
    unsigned int m = counter[0];
    if (m > BUFCAP) m = BUFCAP;
    for (int i = tid; i < BUFCAP; i += 1024) arr[i] = (i < (int)m) ? buf[i] : 0ULL;
    __syncthreads();
    for (int k = 2; k <= BUFCAP; k <<= 1) {
        for (int j = k >> 1; j > 0; j >>= 1) {
            for (int i = tid; i < BUFCAP; i += 1024) {
                int l = i ^ j;
                if (l > i) {
                    unsigned long long a = arr[i], b = arr[l];
                    bool dir = ((i & k) == 0);   // descending overall
                    if (dir ? (a < b) : (a > b)) { arr[i] = b; arr[l] = a; }
                }
            }
            __syncthreads();
        }
    }
    for (int t = tid; t < PRE_NMS; t += 1024) {
        unsigned long long v = arr[t];
        unsigned int key = (unsigned int)(v >> 32);
        unsigned int idx = ~((unsigned int)v);
        top_sc[t] = fkey_inv(key);
        float4 bx = *(const float4*)&props[(size_t)idx * 4];
        *(float4*)&top_boxes[(size_t)t * 4] = bx;
    }
}

// ---------------- K7a: all-pairs IoU bitmask ----------------
__global__ __launch_bounds__(256) void iou_mask(const float* __restrict__ top_boxes,
                                                unsigned long long* __restrict__ mask) {
    int wid = (blockIdx.x * 256 + threadIdx.x) >> 6;
    int lane = threadIdx.x & 63;
    if (wid >= PRE_NMS) return;
    float4 b = *(const float4*)&top_boxes[(size_t)wid * 4];
    float ab = (b.z - b.x + 1.f) * (b.w - b.y + 1.f);
    for (int cj = 0; cj < MASKW; cj++) {
        int j = cj * 64 + lane;
        bool sup = false;
        if (j < PRE_NMS) {
            float4 c = *(const float4*)&top_boxes[(size_t)j * 4];
            float ac = (c.z - c.x + 1.f) * (c.w - c.y + 1.f);
            float ix1 = fmaxf(b.x, c.x), iy1 = fmaxf(b.y, c.y);
            float ix2 = fminf(b.z, c.z), iy2 = fminf(b.w, c.w);
            float inter = fmaxf(ix2 - ix1 + 1.f, 0.f) * fmaxf(iy2 - iy1 + 1.f, 0.f);
            float iou = inter / (ab + ac - inter);
            sup = iou > 0.7f;
        }
        unsigned long long m = __ballot(sup);
        if (lane == 0) mask[(size_t)wid * MASKW + cj] = m;
    }
}

// ---------------- K7b: greedy walk over sorted list ----------------
__global__ __launch_bounds__(64) void nms_greedy(const float* __restrict__ top_boxes,
                                                 const unsigned long long* __restrict__ mask,
                                                 float* __restrict__ out) {
    int lane = threadIdx.x;
    unsigned long long r0 = 0ULL;
    unsigned long long r1;
    if (lane < 29)      r1 = 0ULL;
    else if (lane == 29) r1 = ~((1ULL << 48) - 1);   // word 93: bits 48..63 invalid
    else                r1 = ~0ULL;
    for (int t = 0; t < POST_NMS; t++) {
        unsigned long long w0 = ~r0;
        unsigned long long w1 = ~r1;
        unsigned long long B0 = __ballot(w0 != 0ULL);
        unsigned long long B1 = __ballot(w1 != 0ULL);
        int pos = 0;
        if (B0) {
            int wl = __builtin_ctzll(B0);
            unsigned long long bits = __shfl(w0, wl);
            pos = wl * 64 + __builtin_ctzll(bits);
        } else if (B1) {
            int wl = __builtin_ctzll(B1);
            unsigned long long bits = __shfl(w1, wl);
            pos = (64 + wl) * 64 + __builtin_ctzll(bits);
        }
        if (lane == 0) {
            float4 bb = *(const float4*)&top_boxes[(size_t)pos * 4];
            out[t * 5 + 0] = 0.f;
            out[t * 5 + 1] = bb.x;
            out[t * 5 + 2] = bb.y;
            out[t * 5 + 3] = bb.z;
            out[t * 5 + 4] = bb.w;
        }
        r0 |= mask[(size_t)pos * MASKW + lane];
        if (lane < 30) r1 |= mask[(size_t)pos * MASKW + 64 + lane];
    }
}

// ---------------- launch ----------------
extern "C" void kernel_launch(void* const* d_in, const int* in_sizes, int n_in,
                              void* d_out, int out_size, void* d_ws, size_t ws_size,
                              hipStream_t stream) {
    const float* base = (const float*)d_in[0];
    const float* info = (const float*)d_in[1];
    const float* W1 = (const float*)d_in[3];
    const float* b1 = (const float*)d_in[4];
    const float* Wc = (const float*)d_in[5];
    const float* bc = (const float*)d_in[6];
    const float* Wb = (const float*)d_in[7];
    const float* Bb = (const float*)d_in[8];
    float* out = (float*)d_out;
    char* ws = (char*)d_ws;

    const size_t OFF_PART = 0;                               // 50.3MB (reused: psum, then mask)
    const size_t OFF_H    = (size_t)4 * CMID * NPX * 4;
    const size_t OFF_SD   = OFF_H + (size_t)CMID * NPX * 4;
    const size_t OFF_PROPS= OFF_SD + (size_t)54 * NPX * 4;
    const size_t OFF_SCV  = OFF_PROPS + (size_t)NANCH * 16;
    const size_t OFF_HIST = OFF_SCV + (size_t)NANCH * 4;
    const size_t OFF_PAR  = OFF_HIST + (size_t)NBINS * 4;
    const size_t OFF_BUF  = OFF_PAR + 256;
    const size_t OFF_TB   = OFF_BUF + (size_t)BUFCAP * 8;
    const size_t OFF_TS   = OFF_TB + (size_t)PRE_NMS * 16;

    float* part = (float*)(ws + OFF_PART);
    float* h    = (float*)(ws + OFF_H);
    float* psum = (float*)(ws + OFF_PART);   // reuse (dead after conv1x1_reduce)
    unsigned long long* mask = (unsigned long long*)(ws + OFF_PART); // reuse
    float* sd   = (float*)(ws + OFF_SD);
    float* props= (float*)(ws + OFF_PROPS);
    float* scv  = (float*)(ws + OFF_SCV);
    unsigned int* hist = (unsigned int*)(ws + OFF_HIST);
    unsigned int* params = (unsigned int*)(ws + OFF_PAR);
    unsigned int* counter = params + 1;
    unsigned long long* buf = (unsigned long long*)(ws + OFF_BUF);
    float* top_boxes = (float*)(ws + OFF_TB);
    float* top_sc = (float*)(ws + OFF_TS);

    hipMemsetAsync(hist, 0, (size_t)NBINS * 4 + 256, stream);

    conv3_part<<<dim3(CMID / OCT, 6, CSPL), 256, 0, stream>>>(base, W1, part);
    bias_relu<<<(CMID * NPX) / 256, 256, 0, stream>>>(part, b1, h);
    conv1x1_part<<<dim3(NPX / 256, K2_CS), 256, 0, stream>>>(h, Wc, Wb, psum);
    conv1x1_reduce<<<(54 * NPX) / 256, 256, 0, stream>>>(psum, bc, Bb, sd);
    proposals_k<<<NANCH / 256, 256, 0, stream>>>(sd, info, props, scv, hist);
    scan_hist<<<1, 1024, 0, stream>>>(hist, params);
    gather_top<<<NANCH / 256, 256, 0, stream>>>(scv, params, buf, counter);
    sort_top<<<1, 1024, 0, stream>>>(buf, counter, props, top_boxes, top_sc);
    iou_mask<<<(PRE_NMS * 64 + 255) / 256, 256, 0, stream>>>(top_boxes, mask);
    nms_greedy<<<1, 64, 0, stream>>>(top_boxes, mask, out);
}

// Round 7
// 1618.426 us; speedup vs baseline: 1.1259x; 1.1259x over previous
//
#include <hip/hip_runtime.h>
#include <math.h>

#define HH 64
#define WW 96
#define NPX (HH*WW)        // 6144
#define CIN 1024
#define CMID 512
#define NA 9
#define NANCH (NPX*NA)     // 55296
#define PRE_NMS 6000
#define POST_NMS 300
#define NEGV -1e9f
#define NBINS 16384
#define BUFCAP 8192
#define MASKW 94           // ceil(6000/64)

// conv3 tiling
#define OCT 8
#define CCH 4
#define CSPL 4
#define CPB (CIN/CSPL)     // 256
#define LSTR 38            // LDS row stride
#define WSLOTS (OCT*CCH*9) // 288 weight slots

// conv1x1 tiling
#define K2_CS 16
#define K2_CC (CMID/K2_CS) // 32

__constant__ float c_anch[9][4] = {
    {-84.f, -40.f,  99.f,  55.f},
    {-176.f,-88.f, 191.f, 103.f},
    {-360.f,-184.f,375.f, 199.f},
    {-56.f, -56.f,  71.f,  71.f},
    {-120.f,-120.f,135.f, 135.f},
    {-248.f,-248.f,263.f, 263.f},
    {-36.f, -80.f,  51.f,  95.f},
    {-80.f,-168.f,  95.f, 183.f},
    {-168.f,-344.f,183.f, 359.f}
};

__device__ __forceinline__ unsigned int fkey(float f) {
    unsigned int b = __float_as_uint(f);
    return (b & 0x80000000u) ? ~b : (b | 0x80000000u);
}
__device__ __forceinline__ float fkey_inv(unsigned int k) {
    unsigned int b = (k & 0x80000000u) ? (k & 0x7fffffffu) : ~k;
    return __uint_as_float(b);
}
__device__ __forceinline__ int score_bin(float s) {
    if (!(s > 0.f)) return 0;
    int b = (int)(s * (float)NBINS);
    return b > NBINS - 1 ? NBINS - 1 : b;
}

// ---------------- K1: 3x3 conv partials ----------------
// Round-4's proven no-spill structure (per-iter staging math, NO hoisted
// arrays) + weights staged to LDS once per iteration (round-1-style loop,
// 288 slots handled by for(i=tid;i<288;i+=256)) and read back as
// wave-uniform broadcast ds_read_b128. Removes 288 per-thread global
// weight loads + their address math + vmcnt stalls from the FMA loop.
__global__ __launch_bounds__(256, 4) void conv3_part(const float* __restrict__ x,
                                                     const float* __restrict__ w,
                                                     float* __restrict__ part) {
    __shared__ float inS[CCH][34][LSTR];   // 20672 B
    __shared__ float wS[OCT][CCH][12];     // 1536 B, 16B-aligned rows
    int tid = threadIdx.x;
    int ocb = blockIdx.x * OCT;
    int sp = blockIdx.y;                // 0..5
    int ty0 = (sp / 3) * 32, tx0 = (sp % 3) * 32;
    int cs = blockIdx.z;
    int c0 = cs * CPB;
    int lx = (tid & 15) * 2, ly = (tid >> 4) * 2;

    float acc[OCT][4];
#pragma unroll
    for (int o = 0; o < OCT; o++)
#pragma unroll
        for (int p = 0; p < 4; p++) acc[o][p] = 0.f;

    for (int cc = 0; cc < CPB; cc += CCH) {
        // stage input slab (bounds-checked, zero halo)
        for (int i = tid; i < CCH * 34 * 34; i += 256) {
            int c = i / 1156;
            int rr = i - c * 1156;
            int r = rr / 34;
            int col = rr - r * 34;
            int gy = ty0 + r - 1, gx = tx0 + col - 1;
            float v = 0.f;
            if (gy >= 0 && gy < HH && gx >= 0 && gx < WW)
                v = x[(size_t)(c0 + cc + c) * NPX + gy * WW + gx];
            inS[c][r][col] = v;
        }
        // stage weight block (288 slots, loop handles >256 correctly)
        for (int i = tid; i < WSLOTS; i += 256) {
            int o = i / 36;
            int rem = i - o * 36;
            int c = rem / 9;
            int k = rem - c * 9;
            wS[o][c][k] = w[((size_t)(ocb + o) * CIN + (c0 + cc + c)) * 9 + k];
        }
        __syncthreads();
#pragma unroll
        for (int c = 0; c < CCH; c++) {
            float iv[4][4];
            const float* lrow = &inS[c][ly][lx];
#pragma unroll
            for (int r = 0; r < 4; r++) {
                float2 a = *(const float2*)&lrow[r * LSTR];
                float2 b = *(const float2*)&lrow[r * LSTR + 2];
                iv[r][0] = a.x; iv[r][1] = a.y; iv[r][2] = b.x; iv[r][3] = b.y;
            }
#pragma unroll
            for (int o = 0; o < OCT; o++) {
                float4 w03 = *(const float4*)&wS[o][c][0];
                float4 w47 = *(const float4*)&wS[o][c][4];
                float w8 = wS[o][c][8];
                float wk[9] = {w03.x, w03.y, w03.z, w03.w,
                               w47.x, w47.y, w47.z, w47.w, w8};
#pragma unroll
                for (int ky = 0; ky < 3; ky++)
#pragma unroll
                    for (int kx = 0; kx < 3; kx++) {
                        float wv = wk[ky * 3 + kx];
                        acc[o][0] += iv[0 + ky][0 + kx] * wv;
                        acc[o][1] += iv[0 + ky][1 + kx] * wv;
                        acc[o][2] += iv[1 + ky][0 + kx] * wv;
                        acc[o][3] += iv[1 + ky][1 + kx] * wv;
                    }
            }
        }
        __syncthreads();
    }
#pragma unroll
    for (int o = 0; o < OCT; o++)
#pragma unroll
        for (int p = 0; p < 4; p++) {
            int gy = ty0 + ly + (p >> 1), gx = tx0 + lx + (p & 1);
            part[((size_t)cs * CMID + ocb + o) * NPX + gy * WW + gx] = acc[o][p];
        }
}

// ---------------- K1b: reduce + bias + relu ----------------
__global__ __launch_bounds__(256) void bias_relu(const float* __restrict__ part,
                                                 const float* __restrict__ b1,
                                                 float* __restrict__ h) {
    int i = blockIdx.x * 256 + threadIdx.x;
    if (i >= CMID * NPX) return;
    int oc = i / NPX;
    float s = part[i] + part[(size_t)CMID * NPX + i] +
              part[2 * (size_t)CMID * NPX + i] + part[3 * (size_t)CMID * NPX + i] + b1[oc];
    h[i] = s > 0.f ? s : 0.f;
}

// ---------------- K2: 1x1 convs (c-split partials) ----------------
__global__ __launch_bounds__(256) void conv1x1_part(const float* __restrict__ h,
                                                    const float* __restrict__ wc,
                                                    const float* __restrict__ wb,
                                                    float* __restrict__ psum) {
    __shared__ float wT[K2_CC][56];
    int tid = threadIdx.x;
    int px = blockIdx.x * 256 + tid;
    int g = blockIdx.y;
    int cb = g * K2_CC;
    for (int i = tid; i < K2_CC * 54; i += 256) {
        int c = i / 54, o = i - c * 54;
        float wv = (o < 18) ? wc[o * CMID + cb + c] : wb[(o - 18) * CMID + cb + c];
        wT[c][o] = wv;
    }
    __syncthreads();
    float acc[54];
#pragma unroll
    for (int o = 0; o < 54; o++) acc[o] = 0.f;
    for (int c = 0; c < K2_CC; c++) {
        float hv = h[(size_t)(cb + c) * NPX + px];
#pragma unroll
        for (int o = 0; o < 54; o++) acc[o] += wT[c][o] * hv;
    }
    for (int o = 0; o < 54; o++)
        psum[((size_t)g * 54 + o) * NPX + px] = acc[o];
}

__global__ __launch_bounds__(256) void conv1x1_reduce(const float* __restrict__ psum,
                                                      const float* __restrict__ bc,
                                                      const float* __restrict__ bb,
                                                      float* __restrict__ sd) {
    int i = blockIdx.x * 256 + threadIdx.x;
    if (i >= 54 * NPX) return;
    int o = i / NPX;
    float s = (o < 18) ? bc[o] : bb[o - 18];
    for (int g = 0; g < K2_CS; g++) s += psum[(size_t)g * 54 * NPX + i];
    sd[i] = s;
}

// ---------------- K3: proposals + histogram ----------------
__global__ __launch_bounds__(256) void proposals_k(const float* __restrict__ sd,
                                                   const float* __restrict__ info,
                                                   float* __restrict__ props,
                                                   float* __restrict__ scv,
                                                   unsigned int* __restrict__ hist) {
    int i = blockIdx.x * 256 + threadIdx.x;
    if (i >= NANCH) return;
    int a = i % NA;
    int p = i / NA;
    int hy = p / WW, wx = p - hy * WW;

    float s0 = sd[a * NPX + p], s1 = sd[(a + NA) * NPX + p];
    float m = fmaxf(s0, s1);
    float e0 = expf(s0 - m), e1 = expf(s1 - m);
    float fg = e1 / (e0 + e1);

    float d0 = sd[(18 + 4 * a + 0) * NPX + p];
    float d1 = sd[(18 + 4 * a + 1) * NPX + p];
    float d2 = sd[(18 + 4 * a + 2) * NPX + p];
    float d3 = sd[(18 + 4 * a + 3) * NPX + p];

    float sx = wx * 16.f, sy = hy * 16.f;
    float ax1 = c_anch[a][0] + sx, ay1 = c_anch[a][1] + sy;
    float ax2 = c_anch[a][2] + sx, ay2 = c_anch[a][3] + sy;
    float wdt = ax2 - ax1 + 1.f;
    float hgt = ay2 - ay1 + 1.f;
    float cx = ax1 + 0.5f * wdt;
    float cy = ay1 + 0.5f * hgt;
    float pcx = d0 * wdt + cx;
    float pcy = d1 * hgt + cy;
    float pw = expf(d2) * wdt;
    float ph = expf(d3) * hgt;

    float imh = info[0], imw = info[1], iscale = info[2];
    float x1 = fminf(fmaxf(pcx - 0.5f * pw, 0.f), imw - 1.f);
    float y1 = fminf(fmaxf(pcy - 0.5f * ph, 0.f), imh - 1.f);
    float x2 = fminf(fmaxf(pcx + 0.5f * pw, 0.f), imw - 1.f);
    float y2 = fminf(fmaxf(pcy + 0.5f * ph, 0.f), imh - 1.f);

    float ms = 16.f * iscale;
    bool valid = ((x2 - x1 + 1.f) >= ms) && ((y2 - y1 + 1.f) >= ms);
    float s = valid ? fg : NEGV;

    props[(size_t)i * 4 + 0] = x1;
    props[(size_t)i * 4 + 1] = y1;
    props[(size_t)i * 4 + 2] = x2;
    props[(size_t)i * 4 + 3] = y2;
    scv[i] = s;
    atomicAdd(&hist[score_bin(s)], 1u);
}

// ---------------- K4: find threshold bin ----------------
__global__ __launch_bounds__(1024) void scan_hist(const unsigned int* __restrict__ hist,
                                                  unsigned int* __restrict__ params) {
    __shared__ unsigned int psum[1024];
    int tid = threadIdx.x;
    unsigned int s = 0;
    for (int k = 0; k < 16; k++) s += hist[tid * 16 + k];
    psum[tid] = s;
    __syncthreads();
    if (tid == 0) {
        unsigned int run = 0;
        int B = 0;
        int t;
        for (t = 1023; t >= 0; t--) {
            if (run + psum[t] >= PRE_NMS) break;
            run += psum[t];
        }
        if (t >= 0) {
            unsigned int r2 = run;
            B = t * 16;
            for (int b = t * 16 + 15; b >= t * 16; b--) {
                r2 += hist[b];
                if (r2 >= PRE_NMS) { B = b; break; }
            }
        }
        params[0] = (unsigned int)B;
    }
}

// ---------------- K5: gather candidates ----------------
__global__ __launch_bounds__(256) void gather_top(const float* __restrict__ scv,
                                                  const unsigned int* __restrict__ params,
                                                  unsigned long long* __restrict__ buf,
                                                  unsigned int* __restrict__ counter) {
    int i = blockIdx.x * 256 + threadIdx.x;
    if (i >= NANCH) return;
    float s = scv[i];
    if (score_bin(s) >= (int)params[0]) {
        unsigned int pos = atomicAdd(counter, 1u);
        if (pos < BUFCAP) {
            unsigned long long key = ((unsigned long long)fkey(s) << 32) |
                                     (unsigned int)(~(unsigned int)i);
            buf[pos] = key;
        }
    }
}

// ---------------- K6: bitonic sort, emit top-6000 ----------------
__global__ __launch_bounds__(1024) void sort_top(unsigned long long* __restrict__ buf,
                                                 const unsigned int* __restrict__ counter,
                                                 const float* __restrict__ props,
                                                 float* __restrict__ top_boxes,
                                                 float* __restrict__ top_sc) {
    __shared__ unsigned long long arr[BUFCAP];   // 64 KiB
    int tid = threadIdx.x;
    unsigned int m = counter[0];
    if (m > BUFCAP) m = BUFCAP;
    for (int i = tid; i < BUFCAP; i += 1024) arr[i] = (i < (int)m) ? buf[i] : 0ULL;
    __syncthreads();
    for (int k = 2; k <= BUFCAP; k <<= 1) {
        for (int j = k >> 1; j > 0; j >>= 1) {
            for (int i = tid; i < BUFCAP; i += 1024) {
                int l = i ^ j;
                if (l > i) {
                    unsigned long long a = arr[i], b = arr[l];
                    bool dir = ((i & k) == 0);   // descending overall
                    if (dir ? (a < b) : (a > b)) { arr[i] = b; arr[l] = a; }
                }
            }
            __syncthreads();
        }
    }
    for (int t = tid; t < PRE_NMS; t += 1024) {
        unsigned long long v = arr[t];
        unsigned int key = (unsigned int)(v >> 32);
        unsigned int idx = ~((unsigned int)v);
        top_sc[t] = fkey_inv(key);
        float4 bx = *(const float4*)&props[(size_t)idx * 4];
        *(float4*)&top_boxes[(size_t)t * 4] = bx;
    }
}

// ---------------- K7a: all-pairs IoU bitmask ----------------
__global__ __launch_bounds__(256) void iou_mask(const float* __restrict__ top_boxes,
                                                unsigned long long* __restrict__ mask) {
    int wid = (blockIdx.x * 256 + threadIdx.x) >> 6;
    int lane = threadIdx.x & 63;
    if (wid >= PRE_NMS) return;
    float4 b = *(const float4*)&top_boxes[(size_t)wid * 4];
    float ab = (b.z - b.x + 1.f) * (b.w - b.y + 1.f);
    for (int cj = 0; cj < MASKW; cj++) {
        int j = cj * 64 + lane;
        bool sup = false;
        if (j < PRE_NMS) {
            float4 c = *(const float4*)&top_boxes[(size_t)j * 4];
            float ac = (c.z - c.x + 1.f) * (c.w - c.y + 1.f);
            float ix1 = fmaxf(b.x, c.x), iy1 = fmaxf(b.y, c.y);
            float ix2 = fminf(b.z, c.z), iy2 = fminf(b.w, c.w);
            float inter = fmaxf(ix2 - ix1 + 1.f, 0.f) * fmaxf(iy2 - iy1 + 1.f, 0.f);
            float iou = inter / (ab + ac - inter);
            sup = iou > 0.7f;
        }
        unsigned long long m = __ballot(sup);
        if (lane == 0) mask[(size_t)wid * MASKW + cj] = m;
    }
}

// ---------------- K7b: greedy walk over sorted list ----------------
__global__ __launch_bounds__(64) void nms_greedy(const float* __restrict__ top_boxes,
                                                 const unsigned long long* __restrict__ mask,
                                                 float* __restrict__ out) {
    int lane = threadIdx.x;
    unsigned long long r0 = 0ULL;
    unsigned long long r1;
    if (lane < 29)      r1 = 0ULL;
    else if (lane == 29) r1 = ~((1ULL << 48) - 1);   // word 93: bits 48..63 invalid
    else                r1 = ~0ULL;
    for (int t = 0; t < POST_NMS; t++) {
        unsigned long long w0 = ~r0;
        unsigned long long w1 = ~r1;
        unsigned long long B0 = __ballot(w0 != 0ULL);
        unsigned long long B1 = __ballot(w1 != 0ULL);
        int pos = 0;
        if (B0) {
            int wl = __builtin_ctzll(B0);
            unsigned long long bits = __shfl(w0, wl);
            pos = wl * 64 + __builtin_ctzll(bits);
        } else if (B1) {
            int wl = __builtin_ctzll(B1);
            unsigned long long bits = __shfl(w1, wl);
            pos = (64 + wl) * 64 + __builtin_ctzll(bits);
        }
        if (lane == 0) {
            float4 bb = *(const float4*)&top_boxes[(size_t)pos * 4];
            out[t * 5 + 0] = 0.f;
            out[t * 5 + 1] = bb.x;
            out[t * 5 + 2] = bb.y;
            out[t * 5 + 3] = bb.z;
            out[t * 5 + 4] = bb.w;
        }
        r0 |= mask[(size_t)pos * MASKW + lane];
        if (lane < 30) r1 |= mask[(size_t)pos * MASKW + 64 + lane];
    }
}

// ---------------- launch ----------------
extern "C" void kernel_launch(void* const* d_in, const int* in_sizes, int n_in,
                              void* d_out, int out_size, void* d_ws, size_t ws_size,
                              hipStream_t stream) {
    const float* base = (const float*)d_in[0];
    const float* info = (const float*)d_in[1];
    const float* W1 = (const float*)d_in[3];
    const float* b1 = (const float*)d_in[4];
    const float* Wc = (const float*)d_in[5];
    const float* bc = (const float*)d_in[6];
    const float* Wb = (const float*)d_in[7];
    const float* Bb = (const float*)d_in[8];
    float* out = (float*)d_out;
    char* ws = (char*)d_ws;

    const size_t OFF_PART = 0;                               // 50.3MB (reused: psum, then mask)
    const size_t OFF_H    = (size_t)4 * CMID * NPX * 4;
    const size_t OFF_SD   = OFF_H + (size_t)CMID * NPX * 4;
    const size_t OFF_PROPS= OFF_SD + (size_t)54 * NPX * 4;
    const size_t OFF_SCV  = OFF_PROPS + (size_t)NANCH * 16;
    const size_t OFF_HIST = OFF_SCV + (size_t)NANCH * 4;
    const size_t OFF_PAR  = OFF_HIST + (size_t)NBINS * 4;
    const size_t OFF_BUF  = OFF_PAR + 256;
    const size_t OFF_TB   = OFF_BUF + (size_t)BUFCAP * 8;
    const size_t OFF_TS   = OFF_TB + (size_t)PRE_NMS * 16;

    float* part = (float*)(ws + OFF_PART);
    float* h    = (float*)(ws + OFF_H);
    float* psum = (float*)(ws + OFF_PART);   // reuse (dead after conv1x1_reduce)
    unsigned long long* mask = (unsigned long long*)(ws + OFF_PART); // reuse
    float* sd   = (float*)(ws + OFF_SD);
    float* props= (float*)(ws + OFF_PROPS);
    float* scv  = (float*)(ws + OFF_SCV);
    unsigned int* hist = (unsigned int*)(ws + OFF_HIST);
    unsigned int* params = (unsigned int*)(ws + OFF_PAR);
    unsigned int* counter = params + 1;
    unsigned long long* buf = (unsigned long long*)(ws + OFF_BUF);
    float* top_boxes = (float*)(ws + OFF_TB);
    float* top_sc = (float*)(ws + OFF_TS);

    hipMemsetAsync(hist, 0, (size_t)NBINS * 4 + 256, stream);

    conv3_part<<<dim3(CMID / OCT, 6, CSPL), 256, 0, stream>>>(base, W1, part);
    bias_relu<<<(CMID * NPX) / 256, 256, 0, stream>>>(part, b1, h);
    conv1x1_part<<<dim3(NPX / 256, K2_CS), 256, 0, stream>>>(h, Wc, Wb, psum);
    conv1x1_reduce<<<(54 * NPX) / 256, 256, 0, stream>>>(psum, bc, Bb, sd);
    proposals_k<<<NANCH / 256, 256, 0, stream>>>(sd, info, props, scv, hist);
    scan_hist<<<1, 1024, 0, stream>>>(hist, params);
    gather_top<<<NANCH / 256, 256, 0, stream>>>(scv, params, buf, counter);
    sort_top<<<1, 1024, 0, stream>>>(buf, counter, props, top_boxes, top_sc);
    iou_mask<<<(PRE_NMS * 64 + 255) / 256, 256, 0, stream>>>(top_boxes, mask);
    nms_greedy<<<1, 64, 0, stream>>>(top_boxes, mask, out);
}

// Round 8
// 1304.968 us; speedup vs baseline: 1.3964x; 1.2402x over previous
//
#include <hip/hip_runtime.h>
#include <math.h>

#define HH 64
#define WW 96
#define NPX (HH*WW)        // 6144
#define CIN 1024
#define CMID 512
#define NA 9
#define NANCH (NPX*NA)     // 55296
#define PRE_NMS 6000
#define POST_NMS 300
#define NEGV -1e9f
#define NBINS 16384
#define BUFCAP 8192
#define MASKW 94           // ceil(6000/64)

// conv3 tiling
#define OCT 16
#define CCH 4
#define CSPL 4
#define CPB (CIN/CSPL)     // 256
#define LSTR 38            // LDS row stride

// conv1x1 tiling
#define K2_CS 16
#define K2_CC (CMID/K2_CS) // 32

__constant__ float c_anch[9][4] = {
    {-84.f, -40.f,  99.f,  55.f},
    {-176.f,-88.f, 191.f, 103.f},
    {-360.f,-184.f,375.f, 199.f},
    {-56.f, -56.f,  71.f,  71.f},
    {-120.f,-120.f,135.f, 135.f},
    {-248.f,-248.f,263.f, 263.f},
    {-36.f, -80.f,  51.f,  95.f},
    {-80.f,-168.f,  95.f, 183.f},
    {-168.f,-344.f,183.f, 359.f}
};

__device__ __forceinline__ unsigned int fkey(float f) {
    unsigned int b = __float_as_uint(f);
    return (b & 0x80000000u) ? ~b : (b | 0x80000000u);
}
__device__ __forceinline__ float fkey_inv(unsigned int k) {
    unsigned int b = (k & 0x80000000u) ? (k & 0x7fffffffu) : ~k;
    return __uint_as_float(b);
}
__device__ __forceinline__ int score_bin(float s) {
    if (!(s > 0.f)) return 0;
    int b = (int)(s * (float)NBINS);
    return b > NBINS - 1 ? NBINS - 1 : b;
}

// ---------------- K1: 3x3 conv partials ----------------
// Round-4's proven no-spill structure (per-iter staging math, scalar/SGPR
// weight loads via block-uniform addresses). Single delta: OCT 8->16 to
// double FMA work per staging op (FMA fraction of VALU ~62% -> ~82%).
__global__ __launch_bounds__(256, 4) void conv3_part(const float* __restrict__ x,
                                                     const float* __restrict__ w,
                                                     float* __restrict__ part) {
    __shared__ float inS[CCH][34][LSTR];
    int tid = threadIdx.x;
    int ocb = blockIdx.x * OCT;
    int sp = blockIdx.y;                // 0..5
    int ty0 = (sp / 3) * 32, tx0 = (sp % 3) * 32;
    int cs = blockIdx.z;
    int c0 = cs * CPB;
    int lx = (tid & 15) * 2, ly = (tid >> 4) * 2;

    float acc[OCT][4];
#pragma unroll
    for (int o = 0; o < OCT; o++)
#pragma unroll
        for (int p = 0; p < 4; p++) acc[o][p] = 0.f;

    for (int cc = 0; cc < CPB; cc += CCH) {
        for (int i = tid; i < CCH * 34 * 34; i += 256) {
            int c = i / 1156;
            int rr = i - c * 1156;
            int r = rr / 34;
            int col = rr - r * 34;
            int gy = ty0 + r - 1, gx = tx0 + col - 1;
            float v = 0.f;
            if (gy >= 0 && gy < HH && gx >= 0 && gx < WW)
                v = x[(size_t)(c0 + cc + c) * NPX + gy * WW + gx];
            inS[c][r][col] = v;
        }
        __syncthreads();
        for (int c = 0; c < CCH; c++) {
            float iv[4][4];
            const float* lrow = &inS[c][ly][lx];
#pragma unroll
            for (int r = 0; r < 4; r++) {
                float2 a = *(const float2*)&lrow[r * LSTR];
                float2 b = *(const float2*)&lrow[r * LSTR + 2];
                iv[r][0] = a.x; iv[r][1] = a.y; iv[r][2] = b.x; iv[r][3] = b.y;
            }
            const float* wp = w + ((size_t)ocb * CIN + (c0 + cc + c)) * 9;
#pragma unroll
            for (int o = 0; o < OCT; o++) {
                const float* wo = wp + (size_t)o * CIN * 9;
                float wk[9];
#pragma unroll
                for (int k = 0; k < 9; k++) wk[k] = wo[k];
#pragma unroll
                for (int ky = 0; ky < 3; ky++)
#pragma unroll
                    for (int kx = 0; kx < 3; kx++) {
                        float wv = wk[ky * 3 + kx];
                        acc[o][0] += iv[0 + ky][0 + kx] * wv;
                        acc[o][1] += iv[0 + ky][1 + kx] * wv;
                        acc[o][2] += iv[1 + ky][0 + kx] * wv;
                        acc[o][3] += iv[1 + ky][1 + kx] * wv;
                    }
            }
        }
        __syncthreads();
    }
#pragma unroll
    for (int o = 0; o < OCT; o++)
#pragma unroll
        for (int p = 0; p < 4; p++) {
            int gy = ty0 + ly + (p >> 1), gx = tx0 + lx + (p & 1);
            part[((size_t)cs * CMID + ocb + o) * NPX + gy * WW + gx] = acc[o][p];
        }
}

// ---------------- K1b: reduce + bias + relu ----------------
__global__ __launch_bounds__(256) void bias_relu(const float* __restrict__ part,
                                                 const float* __restrict__ b1,
                                                 float* __restrict__ h) {
    int i = blockIdx.x * 256 + threadIdx.x;
    if (i >= CMID * NPX) return;
    int oc = i / NPX;
    float s = part[i] + part[(size_t)CMID * NPX + i] +
              part[2 * (size_t)CMID * NPX + i] + part[3 * (size_t)CMID * NPX + i] + b1[oc];
    h[i] = s > 0.f ? s : 0.f;
}

// ---------------- K2: 1x1 convs (c-split partials) ----------------
__global__ __launch_bounds__(256) void conv1x1_part(const float* __restrict__ h,
                                                    const float* __restrict__ wc,
                                                    const float* __restrict__ wb,
                                                    float* __restrict__ psum) {
    __shared__ float wT[K2_CC][56];
    int tid = threadIdx.x;
    int px = blockIdx.x * 256 + tid;
    int g = blockIdx.y;
    int cb = g * K2_CC;
    for (int i = tid; i < K2_CC * 54; i += 256) {
        int c = i / 54, o = i - c * 54;
        float wv = (o < 18) ? wc[o * CMID + cb + c] : wb[(o - 18) * CMID + cb + c];
        wT[c][o] = wv;
    }
    __syncthreads();
    float acc[54];
#pragma unroll
    for (int o = 0; o < 54; o++) acc[o] = 0.f;
    for (int c = 0; c < K2_CC; c++) {
        float hv = h[(size_t)(cb + c) * NPX + px];
#pragma unroll
        for (int o = 0; o < 54; o++) acc[o] += wT[c][o] * hv;
    }
    for (int o = 0; o < 54; o++)
        psum[((size_t)g * 54 + o) * NPX + px] = acc[o];
}

__global__ __launch_bounds__(256) void conv1x1_reduce(const float* __restrict__ psum,
                                                      const float* __restrict__ bc,
                                                      const float* __restrict__ bb,
                                                      float* __restrict__ sd) {
    int i = blockIdx.x * 256 + threadIdx.x;
    if (i >= 54 * NPX) return;
    int o = i / NPX;
    float s = (o < 18) ? bc[o] : bb[o - 18];
    for (int g = 0; g < K2_CS; g++) s += psum[(size_t)g * 54 * NPX + i];
    sd[i] = s;
}

// ---------------- K3: proposals + histogram ----------------
__global__ __launch_bounds__(256) void proposals_k(const float* __restrict__ sd,
                                                   const float* __restrict__ info,
                                                   float* __restrict__ props,
                                                   float* __restrict__ scv,
                                                   unsigned int* __restrict__ hist) {
    int i = blockIdx.x * 256 + threadIdx.x;
    if (i >= NANCH) return;
    int a = i % NA;
    int p = i / NA;
    int hy = p / WW, wx = p - hy * WW;

    float s0 = sd[a * NPX + p], s1 = sd[(a + NA) * NPX + p];
    float m = fmaxf(s0, s1);
    float e0 = expf(s0 - m), e1 = expf(s1 - m);
    float fg = e1 / (e0 + e1);

    float d0 = sd[(18 + 4 * a + 0) * NPX + p];
    float d1 = sd[(18 + 4 * a + 1) * NPX + p];
    float d2 = sd[(18 + 4 * a + 2) * NPX + p];
    float d3 = sd[(18 + 4 * a + 3) * NPX + p];

    float sx = wx * 16.f, sy = hy * 16.f;
    float ax1 = c_anch[a][0] + sx, ay1 = c_anch[a][1] + sy;
    float ax2 = c_anch[a][2] + sx, ay2 = c_anch[a][3] + sy;
    float wdt = ax2 - ax1 + 1.f;
    float hgt = ay2 - ay1 + 1.f;
    float cx = ax1 + 0.5f * wdt;
    float cy = ay1 + 0.5f * hgt;
    float pcx = d0 * wdt + cx;
    float pcy = d1 * hgt + cy;
    float pw = expf(d2) * wdt;
    float ph = expf(d3) * hgt;

    float imh = info[0], imw = info[1], iscale = info[2];
    float x1 = fminf(fmaxf(pcx - 0.5f * pw, 0.f), imw - 1.f);
    float y1 = fminf(fmaxf(pcy - 0.5f * ph, 0.f), imh - 1.f);
    float x2 = fminf(fmaxf(pcx + 0.5f * pw, 0.f), imw - 1.f);
    float y2 = fminf(fmaxf(pcy + 0.5f * ph, 0.f), imh - 1.f);

    float ms = 16.f * iscale;
    bool valid = ((x2 - x1 + 1.f) >= ms) && ((y2 - y1 + 1.f) >= ms);
    float s = valid ? fg : NEGV;

    props[(size_t)i * 4 + 0] = x1;
    props[(size_t)i * 4 + 1] = y1;
    props[(size_t)i * 4 + 2] = x2;
    props[(size_t)i * 4 + 3] = y2;
    scv[i] = s;
    atomicAdd(&hist[score_bin(s)], 1u);
}

// ---------------- K4: find threshold bin ----------------
__global__ __launch_bounds__(1024) void scan_hist(const unsigned int* __restrict__ hist,
                                                  unsigned int* __restrict__ params) {
    __shared__ unsigned int psum[1024];
    int tid = threadIdx.x;
    unsigned int s = 0;
    for (int k = 0; k < 16; k++) s += hist[tid * 16 + k];
    psum[tid] = s;
    __syncthreads();
    if (tid == 0) {
        unsigned int run = 0;
        int B = 0;
        int t;
        for (t = 1023; t >= 0; t--) {
            if (run + psum[t] >= PRE_NMS) break;
            run += psum[t];
        }
        if (t >= 0) {
            unsigned int r2 = run;
            B = t * 16;
            for (int b = t * 16 + 15; b >= t * 16; b--) {
                r2 += hist[b];
                if (r2 >= PRE_NMS) { B = b; break; }
            }
        }
        params[0] = (unsigned int)B;
    }
}

// ---------------- K5: gather candidates ----------------
__global__ __launch_bounds__(256) void gather_top(const float* __restrict__ scv,
                                                  const unsigned int* __restrict__ params,
                                                  unsigned long long* __restrict__ buf,
                                                  unsigned int* __restrict__ counter) {
    int i = blockIdx.x * 256 + threadIdx.x;
    if (i >= NANCH) return;
    float s = scv[i];
    if (score_bin(s) >= (int)params[0]) {
        unsigned int pos = atomicAdd(counter, 1u);
        if (pos < BUFCAP) {
            unsigned long long key = ((unsigned long long)fkey(s) << 32) |
                                     (unsigned int)(~(unsigned int)i);
            buf[pos] = key;
        }
    }
}

// ---------------- K6: bitonic sort, emit top-6000 ----------------
__global__ __launch_bounds__(1024) void sort_top(unsigned long long* __restrict__ buf,
                                                 const unsigned int* __restrict__ counter,
                                                 const float* __restrict__ props,
                                                 float* __restrict__ top_boxes,
                                                 float* __restrict__ top_sc) {
    __shared__ unsigned long long arr[BUFCAP];   // 64 KiB
    int tid = threadIdx.x;
    unsigned int m = counter[0];
    if (m > BUFCAP) m = BUFCAP;
    for (int i = tid; i < BUFCAP; i += 1024) arr[i] = (i < (int)m) ? buf[i] : 0ULL;
    __syncthreads();
    for (int k = 2; k <= BUFCAP; k <<= 1) {
        for (int j = k >> 1; j > 0; j >>= 1) {
            for (int i = tid; i < BUFCAP; i += 1024) {
                int l = i ^ j;
                if (l > i) {
                    unsigned long long a = arr[i], b = arr[l];
                    bool dir = ((i & k) == 0);   // descending overall
                    if (dir ? (a < b) : (a > b)) { arr[i] = b; arr[l] = a; }
                }
            }
            __syncthreads();
        }
    }
    for (int t = tid; t < PRE_NMS; t += 1024) {
        unsigned long long v = arr[t];
        unsigned int key = (unsigned int)(v >> 32);
        unsigned int idx = ~((unsigned int)v);
        top_sc[t] = fkey_inv(key);
        float4 bx = *(const float4*)&props[(size_t)idx * 4];
        *(float4*)&top_boxes[(size_t)t * 4] = bx;
    }
}

// ---------------- K7a: all-pairs IoU bitmask ----------------
__global__ __launch_bounds__(256) void iou_mask(const float* __restrict__ top_boxes,
                                                unsigned long long* __restrict__ mask) {
    int wid = (blockIdx.x * 256 + threadIdx.x) >> 6;
    int lane = threadIdx.x & 63;
    if (wid >= PRE_NMS) return;
    float4 b = *(const float4*)&top_boxes[(size_t)wid * 4];
    float ab = (b.z - b.x + 1.f) * (b.w - b.y + 1.f);
    for (int cj = 0; cj < MASKW; cj++) {
        int j = cj * 64 + lane;
        bool sup = false;
        if (j < PRE_NMS) {
            float4 c = *(const float4*)&top_boxes[(size_t)j * 4];
            float ac = (c.z - c.x + 1.f) * (c.w - c.y + 1.f);
            float ix1 = fmaxf(b.x, c.x), iy1 = fmaxf(b.y, c.y);
            float ix2 = fminf(b.z, c.z), iy2 = fminf(b.w, c.w);
            float inter = fmaxf(ix2 - ix1 + 1.f, 0.f) * fmaxf(iy2 - iy1 + 1.f, 0.f);
            float iou = inter / (ab + ac - inter);
            sup = iou > 0.7f;
        }
        unsigned long long m = __ballot(sup);
        if (lane == 0) mask[(size_t)wid * MASKW + cj] = m;
    }
}

// ---------------- K7b: greedy walk over sorted list ----------------
__global__ __launch_bounds__(64) void nms_greedy(const float* __restrict__ top_boxes,
                                                 const unsigned long long* __restrict__ mask,
                                                 float* __restrict__ out) {
    int lane = threadIdx.x;
    unsigned long long r0 = 0ULL;
    unsigned long long r1;
    if (lane < 29)      r1 = 0ULL;
    else if (lane == 29) r1 = ~((1ULL << 48) - 1);   // word 93: bits 48..63 invalid
    else                r1 = ~0ULL;
    for (int t = 0; t < POST_NMS; t++) {
        unsigned long long w0 = ~r0;
        unsigned long long w1 = ~r1;
        unsigned long long B0 = __ballot(w0 != 0ULL);
        unsigned long long B1 = __ballot(w1 != 0ULL);
        int pos = 0;
        if (B0) {
            int wl = __builtin_ctzll(B0);
            unsigned long long bits = __shfl(w0, wl);
            pos = wl * 64 + __builtin_ctzll(bits);
        } else if (B1) {
            int wl = __builtin_ctzll(B1);
            unsigned long long bits = __shfl(w1, wl);
            pos = (64 + wl) * 64 + __builtin_ctzll(bits);
        }
        if (lane == 0) {
            float4 bb = *(const float4*)&top_boxes[(size_t)pos * 4];
            out[t * 5 + 0] = 0.f;
            out[t * 5 + 1] = bb.x;
            out[t * 5 + 2] = bb.y;
            out[t * 5 + 3] = bb.z;
            out[t * 5 + 4] = bb.w;
        }
        r0 |= mask[(size_t)pos * MASKW + lane];
        if (lane < 30) r1 |= mask[(size_t)pos * MASKW + 64 + lane];
    }
}

// ---------------- launch ----------------
extern "C" void kernel_launch(void* const* d_in, const int* in_sizes, int n_in,
                              void* d_out, int out_size, void* d_ws, size_t ws_size,
                              hipStream_t stream) {
    const float* base = (const float*)d_in[0];
    const float* info = (const float*)d_in[1];
    const float* W1 = (const float*)d_in[3];
    const float* b1 = (const float*)d_in[4];
    const float* Wc = (const float*)d_in[5];
    const float* bc = (const float*)d_in[6];
    const float* Wb = (const float*)d_in[7];
    const float* Bb = (const float*)d_in[8];
    float* out = (float*)d_out;
    char* ws = (char*)d_ws;

    const size_t OFF_PART = 0;                               // 50.3MB (reused: psum, then mask)
    const size_t OFF_H    = (size_t)4 * CMID * NPX * 4;
    const size_t OFF_SD   = OFF_H + (size_t)CMID * NPX * 4;
    const size_t OFF_PROPS= OFF_SD + (size_t)54 * NPX * 4;
    const size_t OFF_SCV  = OFF_PROPS + (size_t)NANCH * 16;
    const size_t OFF_HIST = OFF_SCV + (size_t)NANCH * 4;
    const size_t OFF_PAR  = OFF_HIST + (size_t)NBINS * 4;
    const size_t OFF_BUF  = OFF_PAR + 256;
    const size_t OFF_TB   = OFF_BUF + (size_t)BUFCAP * 8;
    const size_t OFF_TS   = OFF_TB + (size_t)PRE_NMS * 16;

    float* part = (float*)(ws + OFF_PART);
    float* h    = (float*)(ws + OFF_H);
    float* psum = (float*)(ws + OFF_PART);   // reuse (dead after conv1x1_reduce)
    unsigned long long* mask = (unsigned long long*)(ws + OFF_PART); // reuse
    float* sd   = (float*)(ws + OFF_SD);
    float* props= (float*)(ws + OFF_PROPS);
    float* scv  = (float*)(ws + OFF_SCV);
    unsigned int* hist = (unsigned int*)(ws + OFF_HIST);
    unsigned int* params = (unsigned int*)(ws + OFF_PAR);
    unsigned int* counter = params + 1;
    unsigned long long* buf = (unsigned long long*)(ws + OFF_BUF);
    float* top_boxes = (float*)(ws + OFF_TB);
    float* top_sc = (float*)(ws + OFF_TS);

    hipMemsetAsync(hist, 0, (size_t)NBINS * 4 + 256, stream);

    conv3_part<<<dim3(CMID / OCT, 6, CSPL), 256, 0, stream>>>(base, W1, part);
    bias_relu<<<(CMID * NPX) / 256, 256, 0, stream>>>(part, b1, h);
    conv1x1_part<<<dim3(NPX / 256, K2_CS), 256, 0, stream>>>(h, Wc, Wb, psum);
    conv1x1_reduce<<<(54 * NPX) / 256, 256, 0, stream>>>(psum, bc, Bb, sd);
    proposals_k<<<NANCH / 256, 256, 0, stream>>>(sd, info, props, scv, hist);
    scan_hist<<<1, 1024, 0, stream>>>(hist, params);
    gather_top<<<NANCH / 256, 256, 0, stream>>>(scv, params, buf, counter);
    sort_top<<<1, 1024, 0, stream>>>(buf, counter, props, top_boxes, top_sc);
    iou_mask<<<(PRE_NMS * 64 + 255) / 256, 256, 0, stream>>>(top_boxes, mask);
    nms_greedy<<<1, 64, 0, stream>>>(top_boxes, mask, out);
}

// Round 9
// 1165.514 us; speedup vs baseline: 1.5634x; 1.1197x over previous
//
#include <hip/hip_runtime.h>
#include <math.h>

#define HH 64
#define WW 96
#define NPX (HH*WW)        // 6144
#define CIN 1024
#define CMID 512
#define NA 9
#define NANCH (NPX*NA)     // 55296
#define PRE_NMS 6000
#define POST_NMS 300
#define NEGV -1e9f
#define NBINS 16384
#define BUFCAP 8192
#define MASKW 94           // ceil(6000/64)

// conv3 tiling: 16x32 px tile, 16 oc, 256 c per block -> grid 32*12*4 = 1536
#define OCT 16
#define CCH 4
#define CSPL 4
#define CPB (CIN/CSPL)     // 256
#define LSTR 38            // LDS row stride
#define TROWS 18           // 16 rows + 2 halo
#define SPY 16
#define SPX 32

// conv1x1 tiling
#define K2_CS 16
#define K2_CC (CMID/K2_CS) // 32

__constant__ float c_anch[9][4] = {
    {-84.f, -40.f,  99.f,  55.f},
    {-176.f,-88.f, 191.f, 103.f},
    {-360.f,-184.f,375.f, 199.f},
    {-56.f, -56.f,  71.f,  71.f},
    {-120.f,-120.f,135.f, 135.f},
    {-248.f,-248.f,263.f, 263.f},
    {-36.f, -80.f,  51.f,  95.f},
    {-80.f,-168.f,  95.f, 183.f},
    {-168.f,-344.f,183.f, 359.f}
};

__device__ __forceinline__ unsigned int fkey(float f) {
    unsigned int b = __float_as_uint(f);
    return (b & 0x80000000u) ? ~b : (b | 0x80000000u);
}
__device__ __forceinline__ float fkey_inv(unsigned int k) {
    unsigned int b = (k & 0x80000000u) ? (k & 0x7fffffffu) : ~k;
    return __uint_as_float(b);
}
__device__ __forceinline__ int score_bin(float s) {
    if (!(s > 0.f)) return 0;
    int b = (int)(s * (float)NBINS);
    return b > NBINS - 1 ? NBINS - 1 : b;
}

// ---------------- K1: 3x3 conv partials ----------------
// Round-8 structure (proven: per-iter staging math, scalar/SGPR weight
// loads, OCT=16). Single delta: spatial tiles 32x32 -> 16x32 (12 tiles),
// grid 768 -> 1536 blocks (3 -> 6 blocks/CU) to lift the 37.5% occupancy
// ceiling that left s_load/vmcnt latency uncovered. 2 px/thread, acc[16][2].
__global__ __launch_bounds__(256, 4) void conv3_part(const float* __restrict__ x,
                                                     const float* __restrict__ w,
                                                     float* __restrict__ part) {
    __shared__ float inS[CCH][TROWS][LSTR];   // 10944 B
    int tid = threadIdx.x;
    int ocb = blockIdx.x * OCT;
    int sp = blockIdx.y;                // 0..11
    int ty0 = (sp / 3) * SPY, tx0 = (sp % 3) * SPX;
    int cs = blockIdx.z;
    int c0 = cs * CPB;
    int lx = (tid & 15) * 2, ly = tid >> 4;   // 16x16 threads, 2 px each (1 row x 2 cols)

    float acc[OCT][2];
#pragma unroll
    for (int o = 0; o < OCT; o++) { acc[o][0] = 0.f; acc[o][1] = 0.f; }

    for (int cc = 0; cc < CPB; cc += CCH) {
        // stage input slab (bounds-checked, zero halo): 4*18*34 = 2448 elems
        for (int i = tid; i < CCH * TROWS * 34; i += 256) {
            int c = i / (TROWS * 34);
            int rr = i - c * (TROWS * 34);
            int r = rr / 34;
            int col = rr - r * 34;
            int gy = ty0 + r - 1, gx = tx0 + col - 1;
            float v = 0.f;
            if (gy >= 0 && gy < HH && gx >= 0 && gx < WW)
                v = x[(size_t)(c0 + cc + c) * NPX + gy * WW + gx];
            inS[c][r][col] = v;
        }
        __syncthreads();
        for (int c = 0; c < CCH; c++) {
            float iv[3][4];
            const float* lrow = &inS[c][ly][lx];
#pragma unroll
            for (int r = 0; r < 3; r++) {
                float2 a = *(const float2*)&lrow[r * LSTR];
                float2 b = *(const float2*)&lrow[r * LSTR + 2];
                iv[r][0] = a.x; iv[r][1] = a.y; iv[r][2] = b.x; iv[r][3] = b.y;
            }
            const float* wp = w + ((size_t)ocb * CIN + (c0 + cc + c)) * 9;
#pragma unroll
            for (int o = 0; o < OCT; o++) {
                const float* wo = wp + (size_t)o * CIN * 9;
                float wk[9];
#pragma unroll
                for (int k = 0; k < 9; k++) wk[k] = wo[k];
#pragma unroll
                for (int ky = 0; ky < 3; ky++)
#pragma unroll
                    for (int kx = 0; kx < 3; kx++) {
                        float wv = wk[ky * 3 + kx];
                        acc[o][0] += iv[ky][0 + kx] * wv;
                        acc[o][1] += iv[ky][1 + kx] * wv;
                    }
            }
        }
        __syncthreads();
    }
    {
        int gy = ty0 + ly, gx = tx0 + lx;
#pragma unroll
        for (int o = 0; o < OCT; o++) {
            float2 v2; v2.x = acc[o][0]; v2.y = acc[o][1];
            *(float2*)&part[((size_t)cs * CMID + ocb + o) * NPX + gy * WW + gx] = v2;
        }
    }
}

// ---------------- K1b: reduce + bias + relu ----------------
__global__ __launch_bounds__(256) void bias_relu(const float* __restrict__ part,
                                                 const float* __restrict__ b1,
                                                 float* __restrict__ h) {
    int i = blockIdx.x * 256 + threadIdx.x;
    if (i >= CMID * NPX) return;
    int oc = i / NPX;
    float s = part[i] + part[(size_t)CMID * NPX + i] +
              part[2 * (size_t)CMID * NPX + i] + part[3 * (size_t)CMID * NPX + i] + b1[oc];
    h[i] = s > 0.f ? s : 0.f;
}

// ---------------- K2: 1x1 convs (c-split partials) ----------------
__global__ __launch_bounds__(256) void conv1x1_part(const float* __restrict__ h,
                                                    const float* __restrict__ wc,
                                                    const float* __restrict__ wb,
                                                    float* __restrict__ psum) {
    __shared__ float wT[K2_CC][56];
    int tid = threadIdx.x;
    int px = blockIdx.x * 256 + tid;
    int g = blockIdx.y;
    int cb = g * K2_CC;
    for (int i = tid; i < K2_CC * 54; i += 256) {
        int c = i / 54, o = i - c * 54;
        float wv = (o < 18) ? wc[o * CMID + cb + c] : wb[(o - 18) * CMID + cb + c];
        wT[c][o] = wv;
    }
    __syncthreads();
    float acc[54];
#pragma unroll
    for (int o = 0; o < 54; o++) acc[o] = 0.f;
    for (int c = 0; c < K2_CC; c++) {
        float hv = h[(size_t)(cb + c) * NPX + px];
#pragma unroll
        for (int o = 0; o < 54; o++) acc[o] += wT[c][o] * hv;
    }
    for (int o = 0; o < 54; o++)
        psum[((size_t)g * 54 + o) * NPX + px] = acc[o];
}

__global__ __launch_bounds__(256) void conv1x1_reduce(const float* __restrict__ psum,
                                                      const float* __restrict__ bc,
                                                      const float* __restrict__ bb,
                                                      float* __restrict__ sd) {
    int i = blockIdx.x * 256 + threadIdx.x;
    if (i >= 54 * NPX) return;
    int o = i / NPX;
    float s = (o < 18) ? bc[o] : bb[o - 18];
    for (int g = 0; g < K2_CS; g++) s += psum[(size_t)g * 54 * NPX + i];
    sd[i] = s;
}

// ---------------- K3: proposals + histogram ----------------
__global__ __launch_bounds__(256) void proposals_k(const float* __restrict__ sd,
                                                   const float* __restrict__ info,
                                                   float* __restrict__ props,
                                                   float* __restrict__ scv,
                                                   unsigned int* __restrict__ hist) {
    int i = blockIdx.x * 256 + threadIdx.x;
    if (i >= NANCH) return;
    int a = i % NA;
    int p = i / NA;
    int hy = p / WW, wx = p - hy * WW;

    float s0 = sd[a * NPX + p], s1 = sd[(a + NA) * NPX + p];
    float m = fmaxf(s0, s1);
    float e0 = expf(s0 - m), e1 = expf(s1 - m);
    float fg = e1 / (e0 + e1);

    float d0 = sd[(18 + 4 * a + 0) * NPX + p];
    float d1 = sd[(18 + 4 * a + 1) * NPX + p];
    float d2 = sd[(18 + 4 * a + 2) * NPX + p];
    float d3 = sd[(18 + 4 * a + 3) * NPX + p];

    float sx = wx * 16.f, sy = hy * 16.f;
    float ax1 = c_anch[a][0] + sx, ay1 = c_anch[a][1] + sy;
    float ax2 = c_anch[a][2] + sx, ay2 = c_anch[a][3] + sy;
    float wdt = ax2 - ax1 + 1.f;
    float hgt = ay2 - ay1 + 1.f;
    float cx = ax1 + 0.5f * wdt;
    float cy = ay1 + 0.5f * hgt;
    float pcx = d0 * wdt + cx;
    float pcy = d1 * hgt + cy;
    float pw = expf(d2) * wdt;
    float ph = expf(d3) * hgt;

    float imh = info[0], imw = info[1], iscale = info[2];
    float x1 = fminf(fmaxf(pcx - 0.5f * pw, 0.f), imw - 1.f);
    float y1 = fminf(fmaxf(pcy - 0.5f * ph, 0.f), imh - 1.f);
    float x2 = fminf(fmaxf(pcx + 0.5f * pw, 0.f), imw - 1.f);
    float y2 = fminf(fmaxf(pcy + 0.5f * ph, 0.f), imh - 1.f);

    float ms = 16.f * iscale;
    bool valid = ((x2 - x1 + 1.f) >= ms) && ((y2 - y1 + 1.f) >= ms);
    float s = valid ? fg : NEGV;

    props[(size_t)i * 4 + 0] = x1;
    props[(size_t)i * 4 + 1] = y1;
    props[(size_t)i * 4 + 2] = x2;
    props[(size_t)i * 4 + 3] = y2;
    scv[i] = s;
    atomicAdd(&hist[score_bin(s)], 1u);
}

// ---------------- K4: find threshold bin ----------------
__global__ __launch_bounds__(1024) void scan_hist(const unsigned int* __restrict__ hist,
                                                  unsigned int* __restrict__ params) {
    __shared__ unsigned int psum[1024];
    int tid = threadIdx.x;
    unsigned int s = 0;
    for (int k = 0; k < 16; k++) s += hist[tid * 16 + k];
    psum[tid] = s;
    __syncthreads();
    if (tid == 0) {
        unsigned int run = 0;
        int B = 0;
        int t;
        for (t = 1023; t >= 0; t--) {
            if (run + psum[t] >= PRE_NMS) break;
            run += psum[t];
        }
        if (t >= 0) {
            unsigned int r2 = run;
            B = t * 16;
            for (int b = t * 16 + 15; b >= t * 16; b--) {
                r2 += hist[b];
                if (r2 >= PRE_NMS) { B = b; break; }
            }
        }
        params[0] = (unsigned int)B;
    }
}

// ---------------- K5: gather candidates ----------------
__global__ __launch_bounds__(256) void gather_top(const float* __restrict__ scv,
                                                  const unsigned int* __restrict__ params,
                                                  unsigned long long* __restrict__ buf,
                                                  unsigned int* __restrict__ counter) {
    int i = blockIdx.x * 256 + threadIdx.x;
    if (i >= NANCH) return;
    float s = scv[i];
    if (score_bin(s) >= (int)params[0]) {
        unsigned int pos = atomicAdd(counter, 1u);
        if (pos < BUFCAP) {
            unsigned long long key = ((unsigned long long)fkey(s) << 32) |
                                     (unsigned int)(~(unsigned int)i);
            buf[pos] = key;
        }
    }
}

// ---------------- K6: bitonic sort, emit top-6000 ----------------
__global__ __launch_bounds__(1024) void sort_top(unsigned long long* __restrict__ buf,
                                                 const unsigned int* __restrict__ counter,
                                                 const float* __restrict__ props,
                                                 float* __restrict__ top_boxes,
                                                 float* __restrict__ top_sc) {
    __shared__ unsigned long long arr[BUFCAP];   // 64 KiB
    int tid = threadIdx.x;
    unsigned int m = counter[0];
    if (m > BUFCAP) m = BUFCAP;
    for (int i = tid; i < BUFCAP; i += 1024) arr[i] = (i < (int)m) ? buf[i] : 0ULL;
    __syncthreads();
    for (int k = 2; k <= BUFCAP; k <<= 1) {
        for (int j = k >> 1; j > 0; j >>= 1) {
            for (int i = tid; i < BUFCAP; i += 1024) {
                int l = i ^ j;
                if (l > i) {
                    unsigned long long a = arr[i], b = arr[l];
                    bool dir = ((i & k) == 0);   // descending overall
                    if (dir ? (a < b) : (a > b)) { arr[i] = b; arr[l] = a; }
                }
            }
            __syncthreads();
        }
    }
    for (int t = tid; t < PRE_NMS; t += 1024) {
        unsigned long long v = arr[t];
        unsigned int key = (unsigned int)(v >> 32);
        unsigned int idx = ~((unsigned int)v);
        top_sc[t] = fkey_inv(key);
        float4 bx = *(const float4*)&props[(size_t)idx * 4];
        *(float4*)&top_boxes[(size_t)t * 4] = bx;
    }
}

// ---------------- K7a: all-pairs IoU bitmask ----------------
__global__ __launch_bounds__(256) void iou_mask(const float* __restrict__ top_boxes,
                                                unsigned long long* __restrict__ mask) {
    int wid = (blockIdx.x * 256 + threadIdx.x) >> 6;
    int lane = threadIdx.x & 63;
    if (wid >= PRE_NMS) return;
    float4 b = *(const float4*)&top_boxes[(size_t)wid * 4];
    float ab = (b.z - b.x + 1.f) * (b.w - b.y + 1.f);
    for (int cj = 0; cj < MASKW; cj++) {
        int j = cj * 64 + lane;
        bool sup = false;
        if (j < PRE_NMS) {
            float4 c = *(const float4*)&top_boxes[(size_t)j * 4];
            float ac = (c.z - c.x + 1.f) * (c.w - c.y + 1.f);
            float ix1 = fmaxf(b.x, c.x), iy1 = fmaxf(b.y, c.y);
            float ix2 = fminf(b.z, c.z), iy2 = fminf(b.w, c.w);
            float inter = fmaxf(ix2 - ix1 + 1.f, 0.f) * fmaxf(iy2 - iy1 + 1.f, 0.f);
            float iou = inter / (ab + ac - inter);
            sup = iou > 0.7f;
        }
        unsigned long long m = __ballot(sup);
        if (lane == 0) mask[(size_t)wid * MASKW + cj] = m;
    }
}

// ---------------- K7b: greedy walk over sorted list ----------------
__global__ __launch_bounds__(64) void nms_greedy(const float* __restrict__ top_boxes,
                                                 const unsigned long long* __restrict__ mask,
                                                 float* __restrict__ out) {
    int lane = threadIdx.x;
    unsigned long long r0 = 0ULL;
    unsigned long long r1;
    if (lane < 29)      r1 = 0ULL;
    else if (lane == 29) r1 = ~((1ULL << 48) - 1);   // word 93: bits 48..63 invalid
    else                r1 = ~0ULL;
    for (int t = 0; t < POST_NMS; t++) {
        unsigned long long w0 = ~r0;
        unsigned long long w1 = ~r1;
        unsigned long long B0 = __ballot(w0 != 0ULL);
        unsigned long long B1 = __ballot(w1 != 0ULL);
        int pos = 0;
        if (B0) {
            int wl = __builtin_ctzll(B0);
            unsigned long long bits = __shfl(w0, wl);
            pos = wl * 64 + __builtin_ctzll(bits);
        } else if (B1) {
            int wl = __builtin_ctzll(B1);
            unsigned long long bits = __shfl(w1, wl);
            pos = (64 + wl) * 64 + __builtin_ctzll(bits);
        }
        if (lane == 0) {
            float4 bb = *(const float4*)&top_boxes[(size_t)pos * 4];
            out[t * 5 + 0] = 0.f;
            out[t * 5 + 1] = bb.x;
            out[t * 5 + 2] = bb.y;
            out[t * 5 + 3] = bb.z;
            out[t * 5 + 4] = bb.w;
        }
        r0 |= mask[(size_t)pos * MASKW + lane];
        if (lane < 30) r1 |= mask[(size_t)pos * MASKW + 64 + lane];
    }
}

// ---------------- launch ----------------
extern "C" void kernel_launch(void* const* d_in, const int* in_sizes, int n_in,
                              void* d_out, int out_size, void* d_ws, size_t ws_size,
                              hipStream_t stream) {
    const float* base = (const float*)d_in[0];
    const float* info = (const float*)d_in[1];
    const float* W1 = (const float*)d_in[3];
    const float* b1 = (const float*)d_in[4];
    const float* Wc = (const float*)d_in[5];
    const float* bc = (const float*)d_in[6];
    const float* Wb = (const float*)d_in[7];
    const float* Bb = (const float*)d_in[8];
    float* out = (float*)d_out;
    char* ws = (char*)d_ws;

    const size_t OFF_PART = 0;                               // 50.3MB (reused: psum, then mask)
    const size_t OFF_H    = (size_t)4 * CMID * NPX * 4;
    const size_t OFF_SD   = OFF_H + (size_t)CMID * NPX * 4;
    const size_t OFF_PROPS= OFF_SD + (size_t)54 * NPX * 4;
    const size_t OFF_SCV  = OFF_PROPS + (size_t)NANCH * 16;
    const size_t OFF_HIST = OFF_SCV + (size_t)NANCH * 4;
    const size_t OFF_PAR  = OFF_HIST + (size_t)NBINS * 4;
    const size_t OFF_BUF  = OFF_PAR + 256;
    const size_t OFF_TB   = OFF_BUF + (size_t)BUFCAP * 8;
    const size_t OFF_TS   = OFF_TB + (size_t)PRE_NMS * 16;

    float* part = (float*)(ws + OFF_PART);
    float* h    = (float*)(ws + OFF_H);
    float* psum = (float*)(ws + OFF_PART);   // reuse (dead after conv1x1_reduce)
    unsigned long long* mask = (unsigned long long*)(ws + OFF_PART); // reuse
    float* sd   = (float*)(ws + OFF_SD);
    float* props= (float*)(ws + OFF_PROPS);
    float* scv  = (float*)(ws + OFF_SCV);
    unsigned int* hist = (unsigned int*)(ws + OFF_HIST);
    unsigned int* params = (unsigned int*)(ws + OFF_PAR);
    unsigned int* counter = params + 1;
    unsigned long long* buf = (unsigned long long*)(ws + OFF_BUF);
    float* top_boxes = (float*)(ws + OFF_TB);
    float* top_sc = (float*)(ws + OFF_TS);

    hipMemsetAsync(hist, 0, (size_t)NBINS * 4 + 256, stream);

    conv3_part<<<dim3(CMID / OCT, 12, CSPL), 256, 0, stream>>>(base, W1, part);
    bias_relu<<<(CMID * NPX) / 256, 256, 0, stream>>>(part, b1, h);
    conv1x1_part<<<dim3(NPX / 256, K2_CS), 256, 0, stream>>>(h, Wc, Wb, psum);
    conv1x1_reduce<<<(54 * NPX) / 256, 256, 0, stream>>>(psum, bc, Bb, sd);
    proposals_k<<<NANCH / 256, 256, 0, stream>>>(sd, info, props, scv, hist);
    scan_hist<<<1, 1024, 0, stream>>>(hist, params);
    gather_top<<<NANCH / 256, 256, 0, stream>>>(scv, params, buf, counter);
    sort_top<<<1, 1024, 0, stream>>>(buf, counter, props, top_boxes, top_sc);
    iou_mask<<<(PRE_NMS * 64 + 255) / 256, 256, 0, stream>>>(top_boxes, mask);
    nms_greedy<<<1, 64, 0, stream>>>(top_boxes, mask, out);
}